// Round 6
// baseline (306.745 us; speedup 1.0000x reference)
//
#include <hip/hip_runtime.h>
#include <hip/hip_fp16.h>
#include <math.h>

namespace {
constexpr int kH = 384, kW = 384, kBn = 2;
constexpr int kHW = kH * kW;       // 147456
constexpr int kOMD = 112;
constexpr int kNB = kBn * (kHW / 64);   // 4608 blocks
constexpr int kNB8 = kNB / 8;           // 576 per XCD
}

typedef _Float16 h2 __attribute__((ext_vector_type(2)));
typedef _Float16 half8 __attribute__((ext_vector_type(8)));
typedef float f32x4 __attribute__((ext_vector_type(4)));

// half2-packed channel-pair weights for k_main (prepped by k_prep)
__device__ unsigned g_Wom2[32 * kOMD];   // [ci2][j] = (Wom[2ci2][j], Wom[2ci2+1][j])
__device__ unsigned g_Wo2[32 * 64];      // [ci2][co] = (Wo[2ci2][co], Wo[2ci2+1][co])
// Wv MFMA A-frag tables (hi + lo*2048): [mt(4)][kh(2)][lane(64)][jj(8)]
//   A = Wv^T: row(co) = mt*16 + (l&15), k(ch) = kh*32 + ((l>>4)&3)*8 + jj
//   (fragment convention HW-validated by round-4 stage D)
__device__ __align__(16) _Float16 g_WvFh[4 * 2 * 64 * 8];
__device__ __align__(16) _Float16 g_WvFl[4 * 2 * 64 * 8];

__device__ __forceinline__ int swz(int t) {
    // XCD-aware: round-robin dispatch -> each XCD gets a contiguous range
    return (t & 7) * kNB8 + (t >> 3);
}

__device__ __forceinline__ unsigned pack2h(float a, float b) {
    unsigned short lo = __builtin_bit_cast(unsigned short, __float2half_rn(a));
    unsigned short hi = __builtin_bit_cast(unsigned short, __float2half_rn(b));
    return (unsigned)lo | ((unsigned)hi << 16);
}

__device__ __forceinline__ unsigned packhh(_Float16 a, _Float16 b) {
    const unsigned short ua = __builtin_bit_cast(unsigned short, a);
    const unsigned short ub = __builtin_bit_cast(unsigned short, b);
    return (unsigned)ua | ((unsigned)ub << 16);
}

#if __has_builtin(__builtin_amdgcn_fdot2)
__device__ __forceinline__ float dot2(unsigned a, unsigned b, float c) {
    return __builtin_amdgcn_fdot2(__builtin_bit_cast(h2, a),
                                  __builtin_bit_cast(h2, b), c, false);
}
#else
__device__ __forceinline__ float dot2(unsigned a, unsigned b, float c) {
    h2 ha = __builtin_bit_cast(h2, a), hb = __builtin_bit_cast(h2, b);
    c = fmaf((float)ha.x, (float)hb.x, c);
    c = fmaf((float)ha.y, (float)hb.y, c);
    return c;
}
#endif

// accumulate one 16-channel corner (32B) with packed fp16 FMAs (v_pk_fma_f16)
__device__ __forceinline__ void acc8h(__half2* pa, const unsigned short* src,
                                      float wgt) {
    const uint4 u0 = ((const uint4*)src)[0];
    const uint4 u1 = ((const uint4*)src)[1];
    const __half2 w2 = __half2half2(__float2half_rn(wgt));
    pa[0] = __hfma2(w2, __builtin_bit_cast(__half2, u0.x), pa[0]);
    pa[1] = __hfma2(w2, __builtin_bit_cast(__half2, u0.y), pa[1]);
    pa[2] = __hfma2(w2, __builtin_bit_cast(__half2, u0.z), pa[2]);
    pa[3] = __hfma2(w2, __builtin_bit_cast(__half2, u0.w), pa[3]);
    pa[4] = __hfma2(w2, __builtin_bit_cast(__half2, u1.x), pa[4]);
    pa[5] = __hfma2(w2, __builtin_bit_cast(__half2, u1.y), pa[5]);
    pa[6] = __hfma2(w2, __builtin_bit_cast(__half2, u1.z), pa[6]);
    pa[7] = __hfma2(w2, __builtin_bit_cast(__half2, u1.w), pa[7]);
}

__device__ __forceinline__ half8 ld_frag_g(const _Float16* ptr) {
    return __builtin_bit_cast(half8, *(const uint4*)ptr);
}

// K0: one-time weight packing (single block; stream-ordered before consumers)
__global__ __launch_bounds__(256) void k_prep(
        const float* __restrict__ Wv, const float* __restrict__ Wom,
        const float* __restrict__ Wo) {
    const int tid = threadIdx.x;
    for (int i = tid; i < 4 * 2 * 64 * 8; i += 256) {
        const int jj = i & 7, l = (i >> 3) & 63, kh = (i >> 9) & 1, mt = i >> 10;
        const int co = mt * 16 + (l & 15);
        const int ch = kh * 32 + ((l >> 4) & 3) * 8 + jj;
        const float w = Wv[ch * 64 + co];
        const _Float16 hi = (_Float16)w;
        g_WvFh[i] = hi;
        g_WvFl[i] = (_Float16)((w - (float)hi) * 2048.f);   // scaled: no denorms
    }
    for (int i = tid; i < 32 * kOMD; i += 256) {
        const int ci2 = i / kOMD, j = i % kOMD;
        g_Wom2[i] = pack2h(Wom[(2 * ci2) * kOMD + j],
                           Wom[(2 * ci2 + 1) * kOMD + j]);
    }
    for (int i = tid; i < 32 * 64; i += 256) {
        const int ci2 = i >> 6, j = i & 63;
        g_Wo2[i] = pack2h(Wo[(2 * ci2) * 64 + j],
                          Wo[(2 * ci2 + 1) * 64 + j]);
    }
}

// K1: value = inp @ Wv + bv via MFMA with exact hi/lo fp16 split.
// Block = 64 px; wave wv owns px-tile wv (16 px), loops 4 co-tiles.
// acc (hi*hi) + acc2 (cross terms, scaled 2048) -> fp32-accurate value.
__global__ __launch_bounds__(256) void k_value(
        const float* __restrict__ inp, const float* __restrict__ bv,
        unsigned short* __restrict__ value) {
    __shared__ unsigned xh[8][64][4];   // fp16-hi  [ch8][px][4xhalf2] = 8 KB
    __shared__ unsigned xl[8][64][4];   // fp16-lo*2048
    const int tid = threadIdx.x;
    const int bid = swz(blockIdx.x);
    const int b = bid / (kHW / 64);
    const int pix0 = (bid % (kHW / 64)) * 64;
    const float* ib = inp + (size_t)b * 64 * kHW + pix0;

    // stage: fp32 -> hi/lo fp16 packed, blocked layout for B-fragments
    #pragma unroll
    for (int it = 0; it < 2; ++it) {
        const int i = tid + it * 256;
        const int c8 = i >> 6, px = i & 63;
        const float* src = ib + (size_t)(c8 * 8) * kHW + px;
        unsigned uh[4], ul[4];
        #pragma unroll
        for (int e = 0; e < 4; ++e) {
            const float x0 = src[(size_t)(2 * e) * kHW];
            const float x1 = src[(size_t)(2 * e + 1) * kHW];
            const _Float16 h0 = (_Float16)x0, h1 = (_Float16)x1;
            const _Float16 l0 = (_Float16)((x0 - (float)h0) * 2048.f);
            const _Float16 l1 = (_Float16)((x1 - (float)h1) * 2048.f);
            uh[e] = packhh(h0, h1);
            ul[e] = packhh(l0, l1);
        }
        *(uint4*)&xh[c8][px][0] = make_uint4(uh[0], uh[1], uh[2], uh[3]);
        *(uint4*)&xl[c8][px][0] = make_uint4(ul[0], ul[1], ul[2], ul[3]);
    }
    __syncthreads();

    const int l = tid & 63;
    const int wv = __builtin_amdgcn_readfirstlane(tid >> 6);  // px-tile id
    const int lr = l & 15, q = l >> 4;
    const int px = wv * 16 + lr;

    half8 bhf[2], blf[2];
    #pragma unroll
    for (int kh = 0; kh < 2; ++kh) {
        bhf[kh] = __builtin_bit_cast(half8, *(const uint4*)&xh[kh * 4 + q][px][0]);
        blf[kh] = __builtin_bit_cast(half8, *(const uint4*)&xl[kh * 4 + q][px][0]);
    }
    #pragma unroll
    for (int mt = 0; mt < 4; ++mt) {
        const half8 ah0 = ld_frag_g(g_WvFh + ((mt * 2 + 0) * 64 + l) * 8);
        const half8 ah1 = ld_frag_g(g_WvFh + ((mt * 2 + 1) * 64 + l) * 8);
        const half8 al0 = ld_frag_g(g_WvFl + ((mt * 2 + 0) * 64 + l) * 8);
        const half8 al1 = ld_frag_g(g_WvFl + ((mt * 2 + 1) * 64 + l) * 8);
        f32x4 acc = {0.f, 0.f, 0.f, 0.f};
        f32x4 acc2 = {0.f, 0.f, 0.f, 0.f};
        acc  = __builtin_amdgcn_mfma_f32_16x16x32_f16(ah0, bhf[0], acc, 0, 0, 0);
        acc  = __builtin_amdgcn_mfma_f32_16x16x32_f16(ah1, bhf[1], acc, 0, 0, 0);
        acc2 = __builtin_amdgcn_mfma_f32_16x16x32_f16(ah0, blf[0], acc2, 0, 0, 0);
        acc2 = __builtin_amdgcn_mfma_f32_16x16x32_f16(ah1, blf[1], acc2, 0, 0, 0);
        acc2 = __builtin_amdgcn_mfma_f32_16x16x32_f16(al0, bhf[0], acc2, 0, 0, 0);
        acc2 = __builtin_amdgcn_mfma_f32_16x16x32_f16(al1, bhf[1], acc2, 0, 0, 0);
        const float4 b4 = *(const float4*)(bv + mt * 16 + q * 4);
        const float v0 = acc[0] + acc2[0] * (1.f / 2048.f) + b4.x;
        const float v1 = acc[1] + acc2[1] * (1.f / 2048.f) + b4.y;
        const float v2 = acc[2] + acc2[2] * (1.f / 2048.f) + b4.z;
        const float v3 = acc[3] + acc2[3] * (1.f / 2048.f) + b4.w;
        uint2 st;
        st.x = pack2h(v0, v1);
        st.y = pack2h(v2, v3);
        // co = mt*16 + q*4 + r ; group = mt ; wave store covers contiguous 512B
        *(uint2*)(value + ((size_t)(b * 4 + mt) * kHW + pix0 + px) * 16 + q * 4) = st;
    }
}

// K2: fused depthwise conv -> om matvec (fdot2) -> deformable sampling -> @Wo (fdot2)
// One block = 64 consecutive pixels of one row. 256 threads. (unchanged from r5)
__global__ __launch_bounds__(256) void k_main(
        const float* __restrict__ inp, const float* __restrict__ Wdw,
        const float* __restrict__ bdw, const float* __restrict__ bom,
        const unsigned short* __restrict__ value, float* __restrict__ out) {
    __shared__ unsigned lds2[32][64];   // half2 channel-pairs [ci2][p]; A->B then C->D

    const int tid = threadIdx.x;
    const int bid = swz(blockIdx.x);
    const int b = bid / (kH * (kW / 64));
    const int rem = bid % (kH * (kW / 64));
    const int h = rem / (kW / 64);
    const int w0 = (rem % (kW / 64)) * 64;

    const int p = tid & 63;
    const int gs = __builtin_amdgcn_readfirstlane(tid >> 6);   // wave-uniform -> SGPR

    // ---- stage A: depthwise 3x3 conv (zero pad) -> half2 pairs in lds2 ----
    {
        const int w = w0 + p;
        #pragma unroll 2
        for (int q = 0; q < 8; ++q) {
            float sv[2];
            #pragma unroll
            for (int e = 0; e < 2; ++e) {
                const int c = gs * 16 + 2 * q + e;          // wave-uniform
                const float* ib = inp + (size_t)(b * 64 + c) * kHW;
                float s = bdw[c];
                #pragma unroll
                for (int r = 0; r < 3; ++r) {
                    const int y = h - 1 + r;
                    if (y >= 0 && y < kH) {
                        const float* rowp = ib + (size_t)y * kW;
                        #pragma unroll
                        for (int kx = 0; kx < 3; ++kx) {
                            const int x = w - 1 + kx;
                            const float v = (x >= 0 && x < kW) ? rowp[x] : 0.f;
                            s = fmaf(v, Wdw[c * 9 + r * 3 + kx], s);
                        }
                    }
                }
                sv[e] = s;
            }
            lds2[gs * 8 + q][p] = pack2h(sv[0], sv[1]);
        }
    }
    __syncthreads();

    // ---- stage B: om[27] via v_dot2_f32_f16 (channel pairs), fp32 accum ----
    float om[27];
    {
        const float* bg = bom + gs * 27;                // scalar loads
        #pragma unroll
        for (int j = 0; j < 27; ++j) om[j] = bg[j];
        #pragma unroll 4
        for (int ci2 = 0; ci2 < 32; ++ci2) {
            const unsigned a2 = lds2[ci2][p];           // 1 ds_read_b32 / pair
            const unsigned* wr = g_Wom2 + ci2 * kOMD + gs * 27;  // wave-uniform
            #pragma unroll
            for (int j = 0; j < 27; ++j) om[j] = dot2(a2, wr[j], om[j]);
        }
    }
    __syncthreads();   // lds2 reads done; stage C will overwrite

    // ---- stage C: deformable bilinear sampling (fp16 value, packed fp16 accum) ----
    {
        __half2 pa[8];
        #pragma unroll
        for (int j = 0; j < 8; ++j) pa[j] = __builtin_bit_cast(__half2, 0u);
        const float fw = (float)(w0 + p);
        const float fh = (float)h;
        const unsigned short* vbase = value + (size_t)(b * 4 + gs) * kHW * 16;
        #pragma unroll
        for (int k = 0; k < 9; ++k) {
            const int ky = k / 3, kx = k % 3;
            const float dx = om[2 * k];
            const float dy = om[2 * k + 1];
            const float m = om[18 + k];
            const float px = fw + (float)(kx - 1) + dx;
            const float py = fh + (float)(ky - 1) + dy;
            const float x0f = floorf(px), y0f = floorf(py);
            const int x0 = (int)x0f, y0 = (int)y0f;
            const float wx1 = px - x0f, wy1 = py - y0f;
            const float wx0 = 1.f - wx1, wy0 = 1.f - wy1;
            const bool interior = (x0 >= 0) & (y0 >= 0) &
                                  (x0 < kW - 1) & (y0 < kH - 1);
            if (__all(interior)) {
                // wave-uniform fast path: one base addr, no clamps, no masks
                const unsigned short* b00 = vbase + ((size_t)y0 * kW + x0) * 16;
                const float wy0m = wy0 * m, wy1m = wy1 * m;
                acc8h(pa, b00,                wx0 * wy0m);
                acc8h(pa, b00 + 16,           wx1 * wy0m);
                acc8h(pa, b00 + kW * 16,      wx0 * wy1m);
                acc8h(pa, b00 + kW * 16 + 16, wx1 * wy1m);
            } else {
                #pragma unroll
                for (int cor = 0; cor < 4; ++cor) {
                    const int dy2 = cor >> 1, dx2 = cor & 1;
                    const int xi = x0 + dx2, yi = y0 + dy2;
                    float wgt = (dy2 ? wy1 : wy0) * (dx2 ? wx1 : wx0) * m;
                    if (xi < 0 || xi >= kW || yi < 0 || yi >= kH) wgt = 0.f;
                    const int xc = min(max(xi, 0), kW - 1);
                    const int yc = min(max(yi, 0), kH - 1);
                    acc8h(pa, vbase + ((size_t)yc * kW + xc) * 16, wgt);
                }
            }
        }
        // sampled pairs already packed -> straight to LDS (dw is dead now)
        #pragma unroll
        for (int j = 0; j < 8; ++j)
            lds2[gs * 8 + j][p] = __builtin_bit_cast(unsigned, pa[j]);
    }
    __syncthreads();

    // ---- stage D: final @Wo via v_dot2_f32_f16, coalesced (B,C,H,W) writeout ----
    {
        float acc[16];
        #pragma unroll
        for (int j = 0; j < 16; ++j) acc[j] = 0.f;
        #pragma unroll 4
        for (int ci2 = 0; ci2 < 32; ++ci2) {
            const unsigned a2 = lds2[ci2][p];
            const unsigned* wr = g_Wo2 + ci2 * 64 + gs * 16;   // wave-uniform
            #pragma unroll
            for (int j = 0; j < 16; ++j) acc[j] = dot2(a2, wr[j], acc[j]);
        }
        float* ob = out + (size_t)(b * 64 + gs * 16) * kHW + (size_t)h * kW + w0 + p;
        #pragma unroll
        for (int j = 0; j < 16; ++j) ob[(size_t)j * kHW] = acc[j];
    }
}

extern "C" void kernel_launch(void* const* d_in, const int* in_sizes, int n_in,
                              void* d_out, int out_size, void* d_ws, size_t ws_size,
                              hipStream_t stream) {
    const float* inp = (const float*)d_in[0];
    const float* Wv  = (const float*)d_in[1];
    const float* bv  = (const float*)d_in[2];
    const float* Wdw = (const float*)d_in[3];
    const float* bdw = (const float*)d_in[4];
    const float* Wom = (const float*)d_in[5];
    const float* bom = (const float*)d_in[6];
    const float* Wo  = (const float*)d_in[7];
    float* outp = (float*)d_out;
    unsigned short* value = (unsigned short*)d_ws;   // [b][g][yx][16] fp16 = 37.7 MB

    k_prep<<<1, 256, 0, stream>>>(Wv, Wom, Wo);
    k_value<<<kNB, 256, 0, stream>>>(inp, bv, value);
    k_main<<<kNB, 256, 0, stream>>>(inp, Wdw, bdw, bom, value, outp);
}

// Round 7
// 299.082 us; speedup vs baseline: 1.0256x; 1.0256x over previous
//
#include <hip/hip_runtime.h>
#include <hip/hip_fp16.h>
#include <math.h>

namespace {
constexpr int kH = 384, kW = 384, kBn = 2;
constexpr int kHW = kH * kW;       // 147456
constexpr int kOMD = 112;
constexpr int kNB = kBn * (kHW / 64);   // 4608 blocks
constexpr int kNB8 = kNB / 8;           // 576 per XCD
}

typedef _Float16 h2 __attribute__((ext_vector_type(2)));
typedef _Float16 half8 __attribute__((ext_vector_type(8)));
typedef float f32x4 __attribute__((ext_vector_type(4)));

// half2-packed channel-pair weights for k_main (prepped by k_prep)
__device__ unsigned g_Wom2[32 * kOMD];   // [ci2][j] = (Wom[2ci2][j], Wom[2ci2+1][j])
__device__ unsigned g_Wo2[32 * 64];      // [ci2][co] = (Wo[2ci2][co], Wo[2ci2+1][co])
// Wv MFMA A-frag tables (hi + lo*2048): [mt(4)][kh(2)][lane(64)][jj(8)]
//   A = Wv^T: row(co) = mt*16 + (l&15), k(ch) = kh*32 + ((l>>4)&3)*8 + jj
__device__ __align__(16) _Float16 g_WvFh[4 * 2 * 64 * 8];
__device__ __align__(16) _Float16 g_WvFl[4 * 2 * 64 * 8];

__device__ __forceinline__ int swz(int t) {
    // XCD-aware: round-robin dispatch -> each XCD gets a contiguous range
    return (t & 7) * kNB8 + (t >> 3);
}

__device__ __forceinline__ unsigned pack2h(float a, float b) {
    unsigned short lo = __builtin_bit_cast(unsigned short, __float2half_rn(a));
    unsigned short hi = __builtin_bit_cast(unsigned short, __float2half_rn(b));
    return (unsigned)lo | ((unsigned)hi << 16);
}

#if __has_builtin(__builtin_amdgcn_fdot2)
__device__ __forceinline__ float dot2(unsigned a, unsigned b, float c) {
    return __builtin_amdgcn_fdot2(__builtin_bit_cast(h2, a),
                                  __builtin_bit_cast(h2, b), c, false);
}
#else
__device__ __forceinline__ float dot2(unsigned a, unsigned b, float c) {
    h2 ha = __builtin_bit_cast(h2, a), hb = __builtin_bit_cast(h2, b);
    c = fmaf((float)ha.x, (float)hb.x, c);
    c = fmaf((float)ha.y, (float)hb.y, c);
    return c;
}
#endif

// accumulate one 16-channel corner (32B) with packed fp16 FMAs (v_pk_fma_f16)
__device__ __forceinline__ void acc8h(__half2* pa, const unsigned short* src,
                                      float wgt) {
    const uint4 u0 = ((const uint4*)src)[0];
    const uint4 u1 = ((const uint4*)src)[1];
    const __half2 w2 = __half2half2(__float2half_rn(wgt));
    pa[0] = __hfma2(w2, __builtin_bit_cast(__half2, u0.x), pa[0]);
    pa[1] = __hfma2(w2, __builtin_bit_cast(__half2, u0.y), pa[1]);
    pa[2] = __hfma2(w2, __builtin_bit_cast(__half2, u0.z), pa[2]);
    pa[3] = __hfma2(w2, __builtin_bit_cast(__half2, u0.w), pa[3]);
    pa[4] = __hfma2(w2, __builtin_bit_cast(__half2, u1.x), pa[4]);
    pa[5] = __hfma2(w2, __builtin_bit_cast(__half2, u1.y), pa[5]);
    pa[6] = __hfma2(w2, __builtin_bit_cast(__half2, u1.z), pa[6]);
    pa[7] = __hfma2(w2, __builtin_bit_cast(__half2, u1.w), pa[7]);
}

__device__ __forceinline__ half8 ld_frag_g(const _Float16* ptr) {
    return __builtin_bit_cast(half8, *(const uint4*)ptr);
}

// K0: one-time weight packing (64 blocks, grid-stride; stream-ordered)
__global__ __launch_bounds__(256) void k_prep(
        const float* __restrict__ Wv, const float* __restrict__ Wom,
        const float* __restrict__ Wo) {
    const int gt = blockIdx.x * 256 + threadIdx.x;
    const int gstep = 64 * 256;
    for (int i = gt; i < 4 * 2 * 64 * 8; i += gstep) {
        const int jj = i & 7, l = (i >> 3) & 63, kh = (i >> 9) & 1, mt = i >> 10;
        const int co = mt * 16 + (l & 15);
        const int ch = kh * 32 + ((l >> 4) & 3) * 8 + jj;
        const float w = Wv[ch * 64 + co];
        const _Float16 hi = (_Float16)w;
        g_WvFh[i] = hi;
        g_WvFl[i] = (_Float16)((w - (float)hi) * 2048.f);   // scaled: no denorms
    }
    for (int i = gt; i < 32 * kOMD; i += gstep) {
        const int ci2 = i / kOMD, j = i % kOMD;
        g_Wom2[i] = pack2h(Wom[(2 * ci2) * kOMD + j],
                           Wom[(2 * ci2 + 1) * kOMD + j]);
    }
    for (int i = gt; i < 32 * 64; i += gstep) {
        const int ci2 = i >> 6, j = i & 63;
        g_Wo2[i] = pack2h(Wo[(2 * ci2) * 64 + j],
                          Wo[(2 * ci2 + 1) * 64 + j]);
    }
}

// K1: value = inp @ Wv + bv via MFMA, exact hi/lo fp16 split.
// Barrier-free: B-fragments loaded directly from global (no LDS round-trip).
// Wave wv owns px-tile; k-map identical to the r6 LDS layout (HW-validated).
__global__ __launch_bounds__(256) void k_value(
        const float* __restrict__ inp, const float* __restrict__ bv,
        unsigned short* __restrict__ value) {
    const int tid = threadIdx.x;
    const int bid = swz(blockIdx.x);
    const int b = bid / (kHW / 64);
    const int pix0 = (bid % (kHW / 64)) * 64;
    const int l = tid & 63;
    const int wv = tid >> 6;                  // px-tile id (wave-uniform)
    const int lr = l & 15, q = l >> 4;
    const int gpx = pix0 + wv * 16 + lr;

    // B-frag: k = kh*32 + q*8 + jj -> channel; direct strided loads + hi/lo split
    const float* xb = inp + (size_t)b * 64 * kHW + (size_t)(q * 8) * kHW + gpx;
    half8 bhf[2], blf[2];
    #pragma unroll
    for (int kh = 0; kh < 2; ++kh) {
        float xv[8];
        #pragma unroll
        for (int jj = 0; jj < 8; ++jj)
            xv[jj] = xb[(size_t)(kh * 32 + jj) * kHW];
        half8 hh, ll;
        #pragma unroll
        for (int jj = 0; jj < 8; ++jj) {
            const _Float16 hval = (_Float16)xv[jj];
            hh[jj] = hval;
            ll[jj] = (_Float16)((xv[jj] - (float)hval) * 2048.f);
        }
        bhf[kh] = hh;
        blf[kh] = ll;
    }

    #pragma unroll
    for (int mt = 0; mt < 4; ++mt) {
        const half8 ah0 = ld_frag_g(g_WvFh + ((mt * 2 + 0) * 64 + l) * 8);
        const half8 ah1 = ld_frag_g(g_WvFh + ((mt * 2 + 1) * 64 + l) * 8);
        const half8 al0 = ld_frag_g(g_WvFl + ((mt * 2 + 0) * 64 + l) * 8);
        const half8 al1 = ld_frag_g(g_WvFl + ((mt * 2 + 1) * 64 + l) * 8);
        f32x4 acc = {0.f, 0.f, 0.f, 0.f};
        f32x4 acc2 = {0.f, 0.f, 0.f, 0.f};
        acc  = __builtin_amdgcn_mfma_f32_16x16x32_f16(ah0, bhf[0], acc, 0, 0, 0);
        acc  = __builtin_amdgcn_mfma_f32_16x16x32_f16(ah1, bhf[1], acc, 0, 0, 0);
        acc2 = __builtin_amdgcn_mfma_f32_16x16x32_f16(ah0, blf[0], acc2, 0, 0, 0);
        acc2 = __builtin_amdgcn_mfma_f32_16x16x32_f16(ah1, blf[1], acc2, 0, 0, 0);
        acc2 = __builtin_amdgcn_mfma_f32_16x16x32_f16(al0, bhf[0], acc2, 0, 0, 0);
        acc2 = __builtin_amdgcn_mfma_f32_16x16x32_f16(al1, bhf[1], acc2, 0, 0, 0);
        const float4 b4 = *(const float4*)(bv + mt * 16 + q * 4);
        const float v0 = acc[0] + acc2[0] * (1.f / 2048.f) + b4.x;
        const float v1 = acc[1] + acc2[1] * (1.f / 2048.f) + b4.y;
        const float v2 = acc[2] + acc2[2] * (1.f / 2048.f) + b4.z;
        const float v3 = acc[3] + acc2[3] * (1.f / 2048.f) + b4.w;
        uint2 st;
        st.x = pack2h(v0, v1);
        st.y = pack2h(v2, v3);
        *(uint2*)(value + ((size_t)(b * 4 + mt) * kHW + gpx) * 16 + q * 4) = st;
    }
}

// K2: fused depthwise conv -> om matvec (fdot2) -> deformable sampling -> @Wo (fdot2)
// One block = 64 consecutive pixels of one row. 256 threads.
__global__ __launch_bounds__(256) void k_main(
        const float* __restrict__ inp, const float* __restrict__ Wdw,
        const float* __restrict__ bdw, const float* __restrict__ bom,
        const unsigned short* __restrict__ value, float* __restrict__ out) {
    __shared__ unsigned lds2[32][64];   // half2 channel-pairs [ci2][p]; A->B then C->D

    const int tid = threadIdx.x;
    const int bid = swz(blockIdx.x);
    const int b = bid / (kH * (kW / 64));
    const int rem = bid % (kH * (kW / 64));
    const int h = rem / (kW / 64);
    const int w0 = (rem % (kW / 64)) * 64;

    const int p = tid & 63;
    const int gs = __builtin_amdgcn_readfirstlane(tid >> 6);   // wave-uniform -> SGPR

    // ---- stage A: depthwise 3x3 conv (zero pad) -> half2 pairs in lds2 ----
    if (w0 != 0 && w0 != kW - 64) {
        // interior-x fast path: lane = pixel-pair (i2) x 8 channels (ch8 half)
        // loads: aligned float2 + 2 dwords cover all 6 taps of both pixels
        const int i2 = p & 31;
        const int ch8 = p >> 5;                 // 0: ch+0..7, 1: ch+8..15
        const int xg = w0 + 2 * i2;             // global x of even pixel
        float s0[8], s1[8];
        #pragma unroll 4
        for (int cc = 0; cc < 8; ++cc) {
            const int cA = gs * 16 + cc;        // scalar (wave-uniform)
            const int cB = cA + 8;              // scalar
            const float bsv = ch8 ? bdw[cB] : bdw[cA];
            float a0 = bsv, a1 = bsv;
            const float* ibA = inp + (size_t)(b * 64 + cA) * kHW;
            const float* wkA = Wdw + cA * 9;    // scalar
            const float* wkB = Wdw + cB * 9;    // scalar
            #pragma unroll
            for (int r = 0; r < 3; ++r) {
                const int y = h - 1 + r;
                if (y >= 0 && y < kH) {         // wave-uniform branch
                    const float* rowp = ibA + (size_t)(ch8 * 8) * kHW
                                            + (size_t)y * kW;
                    const float2 fc = *(const float2*)(rowp + xg);  // x, x+1
                    const float xl = rowp[xg - 1];
                    const float xr = rowp[xg + 2];
                    const float k0 = ch8 ? wkB[r * 3 + 0] : wkA[r * 3 + 0];
                    const float k1 = ch8 ? wkB[r * 3 + 1] : wkA[r * 3 + 1];
                    const float k2 = ch8 ? wkB[r * 3 + 2] : wkA[r * 3 + 2];
                    a0 = fmaf(xl,   k0, a0);
                    a0 = fmaf(fc.x, k1, a0);
                    a0 = fmaf(fc.y, k2, a0);
                    a1 = fmaf(fc.x, k0, a1);
                    a1 = fmaf(fc.y, k1, a1);
                    a1 = fmaf(xr,   k2, a1);
                }
            }
            s0[cc] = a0;
            s1[cc] = a1;
        }
        #pragma unroll
        for (int e = 0; e < 4; ++e) {
            const int row = gs * 8 + ch8 * 4 + e;
            lds2[row][2 * i2]     = pack2h(s0[2 * e], s0[2 * e + 1]);
            lds2[row][2 * i2 + 1] = pack2h(s1[2 * e], s1[2 * e + 1]);
        }
    } else {
        // border-x blocks: generic path (identical to r6)
        const int w = w0 + p;
        #pragma unroll 2
        for (int q = 0; q < 8; ++q) {
            float sv[2];
            #pragma unroll
            for (int e = 0; e < 2; ++e) {
                const int c = gs * 16 + 2 * q + e;          // wave-uniform
                const float* ib = inp + (size_t)(b * 64 + c) * kHW;
                float s = bdw[c];
                #pragma unroll
                for (int r = 0; r < 3; ++r) {
                    const int y = h - 1 + r;
                    if (y >= 0 && y < kH) {
                        const float* rowp = ib + (size_t)y * kW;
                        #pragma unroll
                        for (int kx = 0; kx < 3; ++kx) {
                            const int x = w - 1 + kx;
                            const float v = (x >= 0 && x < kW) ? rowp[x] : 0.f;
                            s = fmaf(v, Wdw[c * 9 + r * 3 + kx], s);
                        }
                    }
                }
                sv[e] = s;
            }
            lds2[gs * 8 + q][p] = pack2h(sv[0], sv[1]);
        }
    }
    __syncthreads();

    // ---- stage B: om[27] via v_dot2_f32_f16 (channel pairs), fp32 accum ----
    float om[27];
    {
        const float* bg = bom + gs * 27;                // scalar loads
        #pragma unroll
        for (int j = 0; j < 27; ++j) om[j] = bg[j];
        #pragma unroll 4
        for (int ci2 = 0; ci2 < 32; ++ci2) {
            const unsigned a2 = lds2[ci2][p];           // 1 ds_read_b32 / pair
            const unsigned* wr = g_Wom2 + ci2 * kOMD + gs * 27;  // wave-uniform
            #pragma unroll
            for (int j = 0; j < 27; ++j) om[j] = dot2(a2, wr[j], om[j]);
        }
    }
    __syncthreads();   // lds2 reads done; stage C will overwrite

    // ---- stage C: deformable bilinear sampling (fp16 value, packed fp16 accum) ----
    {
        __half2 pa[8];
        #pragma unroll
        for (int j = 0; j < 8; ++j) pa[j] = __builtin_bit_cast(__half2, 0u);
        const float fw = (float)(w0 + p);
        const float fh = (float)h;
        const unsigned short* vbase = value + (size_t)(b * 4 + gs) * kHW * 16;
        #pragma unroll
        for (int k = 0; k < 9; ++k) {
            const int ky = k / 3, kx = k % 3;
            const float dx = om[2 * k];
            const float dy = om[2 * k + 1];
            const float m = om[18 + k];
            const float px = fw + (float)(kx - 1) + dx;
            const float py = fh + (float)(ky - 1) + dy;
            const float x0f = floorf(px), y0f = floorf(py);
            const int x0 = (int)x0f, y0 = (int)y0f;
            const float wx1 = px - x0f, wy1 = py - y0f;
            const float wx0 = 1.f - wx1, wy0 = 1.f - wy1;
            const bool interior = (x0 >= 0) & (y0 >= 0) &
                                  (x0 < kW - 1) & (y0 < kH - 1);
            if (__all(interior)) {
                // wave-uniform fast path: one base addr, no clamps, no masks
                const unsigned short* b00 = vbase + ((size_t)y0 * kW + x0) * 16;
                const float wy0m = wy0 * m, wy1m = wy1 * m;
                acc8h(pa, b00,                wx0 * wy0m);
                acc8h(pa, b00 + 16,           wx1 * wy0m);
                acc8h(pa, b00 + kW * 16,      wx0 * wy1m);
                acc8h(pa, b00 + kW * 16 + 16, wx1 * wy1m);
            } else {
                #pragma unroll
                for (int cor = 0; cor < 4; ++cor) {
                    const int dy2 = cor >> 1, dx2 = cor & 1;
                    const int xi = x0 + dx2, yi = y0 + dy2;
                    float wgt = (dy2 ? wy1 : wy0) * (dx2 ? wx1 : wx0) * m;
                    if (xi < 0 || xi >= kW || yi < 0 || yi >= kH) wgt = 0.f;
                    const int xc = min(max(xi, 0), kW - 1);
                    const int yc = min(max(yi, 0), kH - 1);
                    acc8h(pa, vbase + ((size_t)yc * kW + xc) * 16, wgt);
                }
            }
        }
        // sampled pairs already packed -> straight to LDS (dw is dead now)
        #pragma unroll
        for (int j = 0; j < 8; ++j)
            lds2[gs * 8 + j][p] = __builtin_bit_cast(unsigned, pa[j]);
    }
    __syncthreads();

    // ---- stage D: final @Wo via v_dot2_f32_f16, coalesced (B,C,H,W) writeout ----
    {
        float acc[16];
        #pragma unroll
        for (int j = 0; j < 16; ++j) acc[j] = 0.f;
        #pragma unroll 4
        for (int ci2 = 0; ci2 < 32; ++ci2) {
            const unsigned a2 = lds2[ci2][p];
            const unsigned* wr = g_Wo2 + ci2 * 64 + gs * 16;   // wave-uniform
            #pragma unroll
            for (int j = 0; j < 16; ++j) acc[j] = dot2(a2, wr[j], acc[j]);
        }
        float* ob = out + (size_t)(b * 64 + gs * 16) * kHW + (size_t)h * kW + w0 + p;
        #pragma unroll
        for (int j = 0; j < 16; ++j) ob[(size_t)j * kHW] = acc[j];
    }
}

extern "C" void kernel_launch(void* const* d_in, const int* in_sizes, int n_in,
                              void* d_out, int out_size, void* d_ws, size_t ws_size,
                              hipStream_t stream) {
    const float* inp = (const float*)d_in[0];
    const float* Wv  = (const float*)d_in[1];
    const float* bv  = (const float*)d_in[2];
    const float* Wdw = (const float*)d_in[3];
    const float* bdw = (const float*)d_in[4];
    const float* Wom = (const float*)d_in[5];
    const float* bom = (const float*)d_in[6];
    const float* Wo  = (const float*)d_in[7];
    float* outp = (float*)d_out;
    unsigned short* value = (unsigned short*)d_ws;   // [b][g][yx][16] fp16 = 37.7 MB

    k_prep<<<64, 256, 0, stream>>>(Wv, Wom, Wo);
    k_value<<<kNB, 256, 0, stream>>>(inp, bv, value);
    k_main<<<kNB, 256, 0, stream>>>(inp, Wdw, bdw, bom, value, outp);
}